// Round 6
// baseline (1549.695 us; speedup 1.0000x reference)
//
#include <hip/hip_runtime.h>
#include <hip/hip_bf16.h>

typedef __hip_bfloat16 bf16;
typedef __attribute__((ext_vector_type(8))) short short8;
typedef __attribute__((ext_vector_type(4))) float f32x4;

#define TT 2048
#define DM 1024
#define DI 2048
#define NLAYER 4
#define NST 16
#define KC 4
#define VOCAB 32000
#define XPS 33   // 1 + 2*NST
#define NCHUNK 64
#define CLEN 32  // TT / NCHUNK

__device__ __forceinline__ float us2f(unsigned short u) {
    union { float f; unsigned int i; } c; c.i = ((unsigned int)u) << 16; return c.f;
}
__device__ __forceinline__ float ldin(const void* p, size_t i, int f32) {
    return f32 ? ((const float*)p)[i] : us2f(((const unsigned short*)p)[i]);
}
__device__ __forceinline__ unsigned short f2us(float f) {
    bf16 h = __float2bfloat16(f);
    return *(unsigned short*)&h;
}
// hend layout: [NST][NCHUNK][DI] -> coalesced in d everywhere
__device__ __forceinline__ size_t hidx(int n, int c, int d) {
    return ((size_t)n * NCHUNK + c) * DI + d;
}

// ---------------- f32 -> bf16 weight conversion, 8 elems/thread, two tensors ----------------
__global__ void cvt8_dual_kernel(const float* __restrict__ sA, unsigned short* __restrict__ dA, int n8A,
                                 const float* __restrict__ sB, unsigned short* __restrict__ dB, int n8B) {
    int i = blockIdx.x * 256 + threadIdx.x;
    const float* s; unsigned short* d;
    if (i < n8A) { s = sA; d = dA; }
    else { i -= n8A; if (i >= n8B) return; s = sB; d = dB; }
    float4 a = ((const float4*)s)[2 * i];
    float4 b = ((const float4*)s)[2 * i + 1];
    unsigned int w0 = (unsigned int)f2us(a.x) | ((unsigned int)f2us(a.y) << 16);
    unsigned int w1 = (unsigned int)f2us(a.z) | ((unsigned int)f2us(a.w) << 16);
    unsigned int w2 = (unsigned int)f2us(b.x) | ((unsigned int)f2us(b.y) << 16);
    unsigned int w3 = (unsigned int)f2us(b.z) | ((unsigned int)f2us(b.w) << 16);
    ((uint4*)d)[i] = make_uint4(w0, w1, w2, w3);
}

// ---------------- fused embedding + layer-0 rmsnorm: writes x (f32) and xn16 (bf16) ----------
__global__ void embed_rms_kernel(const int* __restrict__ idx, const void* __restrict__ emb,
                                 const void* __restrict__ w, float* __restrict__ x,
                                 bf16* __restrict__ ob, int f32) {
    int t = blockIdx.x, tid = threadIdx.x;
    int wv = tid >> 6, lane = tid & 63;
    size_t src = (size_t)idx[t] * DM + tid * 4;
    float4 v;
    if (f32) v = *(const float4*)((const float*)emb + src);
    else {
        ushort4 h = *(const ushort4*)((const unsigned short*)emb + src);
        v = make_float4(us2f(h.x), us2f(h.y), us2f(h.z), us2f(h.w));
    }
    ((float4*)x)[(size_t)t * (DM / 4) + tid] = v;
    float s = v.x * v.x + v.y * v.y + v.z * v.z + v.w * v.w;
#pragma unroll
    for (int o = 1; o < 64; o <<= 1) s += __shfl_xor(s, o, 64);
    __shared__ float red[4];
    if (lane == 0) red[wv] = s;
    __syncthreads();
    float inv = rsqrtf((red[0] + red[1] + red[2] + red[3]) / (float)DM + 1e-5f);
    float w0, w1, w2, w3;
    if (f32) {
        float4 wq = ((const float4*)w)[tid];
        w0 = wq.x; w1 = wq.y; w2 = wq.z; w3 = wq.w;
    } else {
        ushort4 wq = ((const ushort4*)w)[tid];
        w0 = us2f(wq.x); w1 = us2f(wq.y); w2 = us2f(wq.z); w3 = us2f(wq.w);
    }
    uint2 o;
    o.x = (unsigned int)f2us(v.x * inv * w0) | ((unsigned int)f2us(v.y * inv * w1) << 16);
    o.y = (unsigned int)f2us(v.z * inv * w2) | ((unsigned int)f2us(v.w * inv * w3) << 16);
    ((uint2*)(ob + (size_t)t * DM))[tid] = o;
}

// ---------------- rmsnorm: one block/row, float4 + wave shuffle reduce; writes bf16 ----------
__global__ void rmsnorm_kernel(const float* __restrict__ x, const void* __restrict__ w,
                               size_t wofs, bf16* __restrict__ ob, int f32) {
    int t = blockIdx.x, tid = threadIdx.x;
    int wv = tid >> 6, lane = tid & 63;
    float4 v = ((const float4*)(x + (size_t)t * DM))[tid];
    float s = v.x * v.x + v.y * v.y + v.z * v.z + v.w * v.w;
#pragma unroll
    for (int o = 1; o < 64; o <<= 1) s += __shfl_xor(s, o, 64);
    __shared__ float red[4];
    if (lane == 0) red[wv] = s;
    __syncthreads();
    float inv = rsqrtf((red[0] + red[1] + red[2] + red[3]) / (float)DM + 1e-5f);
    float w0, w1, w2, w3;
    if (f32) {
        float4 wq = ((const float4*)((const float*)w + wofs))[tid];
        w0 = wq.x; w1 = wq.y; w2 = wq.z; w3 = wq.w;
    } else {
        ushort4 wq = ((const ushort4*)((const unsigned short*)w + wofs))[tid];
        w0 = us2f(wq.x); w1 = us2f(wq.y); w2 = us2f(wq.z); w3 = us2f(wq.w);
    }
    uint2 o;
    o.x = (unsigned int)f2us(v.x * inv * w0) | ((unsigned int)f2us(v.y * inv * w1) << 16);
    o.y = (unsigned int)f2us(v.z * inv * w2) | ((unsigned int)f2us(v.w * inv * w3) << 16);
    ((uint2*)(ob + (size_t)t * DM))[tid] = o;
}

// ---------------- MFMA bf16 GEMM: C[M,N] = A[M,K](bf16) * B[N,K](bf16)^T (+Res f32) ------------
// m97 2-barrier structure, BK=64, BN=128, BM templated {32,64,128}.
// LDS XOR-swizzle (byte ^= (row&7)<<4): LDS dest linear, global SOURCE pre-swizzled per lane,
// same XOR on ds_read side (zero bank conflicts, verified R5).
// Epilogue: stage 32x128 C rows in LDS, emit fully-coalesced float4 row stores.
template<int BM>
__global__ __launch_bounds__(256, (BM <= 64 ? 4 : 2))
void gemm_mfma(const bf16* __restrict__ A16, const bf16* __restrict__ B16,
               const float* __restrict__ Res, float* __restrict__ Cf, bf16* __restrict__ C16,
               int MT, int NT, int Kk) {
    constexpr int BK = 64;
    constexpr int MR = BM / 32;          // m-fragments per wave
    constexpr int AQ = BM / 32;          // A staging rounds (256 thr x 16B = 32 rows of 128B)
    int Nn = NT << 7;
    __shared__ __align__(16) char smem[(BM + 128) * BK * 2];   // >= 32*132*4 for all BM
    unsigned short* As = (unsigned short*)smem;
    unsigned short* Bs = As + BM * BK;
    float* Cs = (float*)smem;            // epilogue staging: 32 rows x 132 floats

    int tid = threadIdx.x;
    int w = tid >> 6, lane = tid & 63;
    int h = lane >> 4, r = lane & 15;

    int nwg = MT * NT;
    int bid = blockIdx.x;
    int swz = ((nwg & 7) == 0) ? ((bid & 7) * (nwg >> 3) + (bid >> 3)) : bid;
    int mt = swz % MT, nt = swz / MT;    // consecutive swz share nt -> B-panel L2 reuse
    int m0 = mt * BM, n0 = nt << 7;

    const unsigned short* Ap = (const unsigned short*)A16;
    const unsigned short* Bp = (const unsigned short*)B16;

    // linear LDS staging; SOURCE chunk pre-swizzled: chunk_src = (tid&7) ^ (row&7)
    int srow = tid >> 3;
    int skof = (((tid & 7) ^ ((tid >> 3) & 7)) << 3);
    const unsigned short* gA = Ap + (size_t)(m0 + srow) * Kk + skof;
    const unsigned short* gB = Bp + (size_t)(n0 + srow) * Kk + skof;

    f32x4 acc[MR][4];
#pragma unroll
    for (int i = 0; i < MR; i++)
#pragma unroll
        for (int j = 0; j < 4; j++) acc[i][j] = (f32x4){0.f, 0.f, 0.f, 0.f};

    int wr = w >> 1, wc = w & 1;
    int rA0 = ((wr * (BM / 2)) + r) << 6;      // row base (shorts; 64 shorts = 128 B/row)
    int rB0 = (((wc << 6)) + r) << 6;
    int cx = r & 7;                            // read-side XOR (row&7 == r&7 here)

    for (int k0 = 0; k0 < Kk; k0 += BK) {
#pragma unroll
        for (int q = 0; q < AQ; q++)
            __builtin_amdgcn_global_load_lds(
                (const __attribute__((address_space(1))) void*)(gA + k0 + (size_t)(q * 32) * Kk),
                (__attribute__((address_space(3))) void*)(As + q * 2048 + (w << 9)), 16, 0, 0);
#pragma unroll
        for (int q = 0; q < 4; q++)
            __builtin_amdgcn_global_load_lds(
                (const __attribute__((address_space(1))) void*)(gB + k0 + (size_t)(q * 32) * Kk),
                (__attribute__((address_space(3))) void*)(Bs + q * 2048 + (w << 9)), 16, 0, 0);
        __syncthreads();
#pragma unroll
        for (int kk = 0; kk < 2; kk++) {
            short8 af[MR], bfr[4];
#pragma unroll
            for (int mi = 0; mi < MR; mi++)
                af[mi] = *(const short8*)(As + rA0 + (mi << 10) + ((((kk << 2) | h) ^ cx) << 3));
#pragma unroll
            for (int ni = 0; ni < 4; ni++)
                bfr[ni] = *(const short8*)(Bs + rB0 + (ni << 10) + ((((kk << 2) | h) ^ cx) << 3));
#pragma unroll
            for (int mi = 0; mi < MR; mi++)
#pragma unroll
                for (int ni = 0; ni < 4; ni++)
                    acc[mi][ni] = __builtin_amdgcn_mfma_f32_16x16x32_bf16(
                        af[mi], bfr[ni], acc[mi][ni], 0, 0, 0);
        }
        __syncthreads();
    }
    // ---- epilogue: per 32-row pass, scatter acc -> LDS, then coalesced row stores ----
    // C/D frag layout: col = lane&15, row = (lane>>4)*4 + reg
#pragma unroll
    for (int p = 0; p < BM / 32; p++) {
#pragma unroll
        for (int mi = 0; mi < MR; mi++) {
            int mloc = wr * (BM / 2) + mi * 16;
            if ((mloc >> 5) != p) continue;
            int lr0 = (mloc & 31) + (h << 2);
#pragma unroll
            for (int j = 0; j < 4; j++)
#pragma unroll
                for (int ni = 0; ni < 4; ni++)
                    Cs[(lr0 + j) * 132 + (wc << 6) + (ni << 4) + r] = acc[mi][ni][j];
        }
        __syncthreads();
#pragma unroll
        for (int q2 = 0; q2 < 4; q2++) {
            int f = q2 * 256 + tid;
            int rr = f >> 5, c4 = f & 31;
            int grow = m0 + p * 32 + rr;
            size_t go = (size_t)grow * Nn + n0 + (c4 << 2);
            float4 v = *(const float4*)&Cs[rr * 132 + (c4 << 2)];
            if (Res) {
                float4 rv = *(const float4*)(Res + go);
                v.x += rv.x; v.y += rv.y; v.z += rv.z; v.w += rv.w;
            }
            if (Cf) *(float4*)(Cf + go) = v;
            if (C16) {
                uint2 o;
                o.x = (unsigned int)f2us(v.x) | ((unsigned int)f2us(v.y) << 16);
                o.y = (unsigned int)f2us(v.z) | ((unsigned int)f2us(v.w) << 16);
                *(uint2*)((unsigned short*)C16 + go) = o;
            }
        }
        __syncthreads();
    }
}

// ---------------- fused: causal depthwise conv(K=4)+bias+silu (in regs), x_proj -> xp --------
__global__ void cxp_kernel(const float* __restrict__ xz,
                           const void* __restrict__ cw, size_t cwofs,
                           const void* __restrict__ cb, size_t cbofs,
                           const void* __restrict__ xpw, size_t xpwofs,
                           float* __restrict__ xp, int f32) {
    int t = blockIdx.x, tid = threadIdx.x;
    int wv = tid >> 6, lane = tid & 63;
    int d0 = tid * 8;
    float uv[8];
#pragma unroll
    for (int k = 0; k < 8; k++) uv[k] = ldin(cb, cbofs + d0 + k, f32);
#pragma unroll
    for (int j = 0; j < KC; j++) {
        int tt = t - (KC - 1) + j;
        if (tt < 0) continue;
        const float* row = xz + (size_t)tt * (2 * DI) + d0;
        float4 v0 = *(const float4*)row;
        float4 v1 = *(const float4*)(row + 4);
        float vv[8] = {v0.x, v0.y, v0.z, v0.w, v1.x, v1.y, v1.z, v1.w};
#pragma unroll
        for (int k = 0; k < 8; k++)
            uv[k] += ldin(cw, cwofs + (size_t)(d0 + k) * KC + j, f32) * vv[k];
    }
#pragma unroll
    for (int k = 0; k < 8; k++) { float s = uv[k]; uv[k] = s / (1.f + __expf(-s)); }

    float p[XPS];
    if (f32) {
        const float* wb = (const float*)xpw + xpwofs + d0;
#pragma unroll
        for (int n = 0; n < XPS; n++) {
            const float* wp = wb + (size_t)n * DI;
            float4 w0 = *(const float4*)wp, w1 = *(const float4*)(wp + 4);
            p[n] = uv[0] * w0.x + uv[1] * w0.y + uv[2] * w0.z + uv[3] * w0.w
                 + uv[4] * w1.x + uv[5] * w1.y + uv[6] * w1.z + uv[7] * w1.w;
        }
    } else {
        const unsigned short* wb = (const unsigned short*)xpw + xpwofs + d0;
#pragma unroll
        for (int n = 0; n < XPS; n++) {
            uint4 wq = *(const uint4*)(wb + (size_t)n * DI);
            p[n] = uv[0] * us2f(wq.x & 0xffff) + uv[1] * us2f(wq.x >> 16)
                 + uv[2] * us2f(wq.y & 0xffff) + uv[3] * us2f(wq.y >> 16)
                 + uv[4] * us2f(wq.z & 0xffff) + uv[5] * us2f(wq.z >> 16)
                 + uv[6] * us2f(wq.w & 0xffff) + uv[7] * us2f(wq.w >> 16);
        }
    }
    __shared__ float red[4 * XPS];
#pragma unroll
    for (int n = 0; n < XPS; n++) {
        float v = p[n];
#pragma unroll
        for (int s_ = 1; s_ < 64; s_ <<= 1) v += __shfl_xor(v, s_, 64);
        if (lane == 0) red[wv * XPS + n] = v;
    }
    __syncthreads();
    if (tid < XPS)
        xp[t * XPS + tid] = red[tid] + red[XPS + tid] + red[2 * XPS + tid] + red[3 * XPS + tid];
}

// ---------------- chunk-parallel selective scan (conv recomputed via sliding window) --------
__global__ void scanA_kernel(const float* __restrict__ xp, const float* __restrict__ xz,
                             const void* __restrict__ cw, size_t cwofs,
                             const void* __restrict__ cb, size_t cbofs,
                             const void* __restrict__ dtw, size_t dtwofs,
                             const void* __restrict__ dtb, size_t dtbofs,
                             const void* __restrict__ A_log, size_t aofs,
                             float* __restrict__ S, float* __restrict__ hend, int f32) {
    int c = blockIdx.y;
    int d = blockIdx.x * 256 + threadIdx.x;
    __shared__ float xps[CLEN * XPS];
    for (int i = threadIdx.x; i < CLEN * XPS; i += 256) xps[i] = xp[c * CLEN * XPS + i];
    __syncthreads();
    float dw = ldin(dtw, dtwofs + d, f32);
    float db = ldin(dtb, dtbofs + d, f32);
    float c0 = ldin(cw, cwofs + (size_t)d * KC + 0, f32);
    float c1 = ldin(cw, cwofs + (size_t)d * KC + 1, f32);
    float c2 = ldin(cw, cwofs + (size_t)d * KC + 2, f32);
    float c3 = ldin(cw, cwofs + (size_t)d * KC + 3, f32);
    float cbv = ldin(cb, cbofs + d, f32);
    float Ar[NST], hh[NST];
#pragma unroll
    for (int n = 0; n < NST; n++) {
        Ar[n] = -expf(ldin(A_log, aofs + (size_t)d * NST + n, f32));
        hh[n] = 0.f;
    }
    int tb = c * CLEN;
    float w0 = (tb >= 3) ? xz[(size_t)(tb - 3) * (2 * DI) + d] : 0.f;
    float w1 = (tb >= 2) ? xz[(size_t)(tb - 2) * (2 * DI) + d] : 0.f;
    float w2 = (tb >= 1) ? xz[(size_t)(tb - 1) * (2 * DI) + d] : 0.f;
    float ssum = 0.f;
    for (int tt = 0; tt < CLEN; tt++) {
        float cur = xz[(size_t)(tb + tt) * (2 * DI) + d];
        float s0 = cbv + c0 * w0 + c1 * w1 + c2 * w2 + c3 * cur;
        float uvv = s0 / (1.f + __expf(-s0));
        w0 = w1; w1 = w2; w2 = cur;
        float s = xps[tt * XPS] * dw + db;
        float dtv = (s > 20.f) ? s : log1pf(__expf(s));
        float du = dtv * uvv;
        ssum += dtv;
        const float* bb = &xps[tt * XPS + 1];
#pragma unroll
        for (int n = 0; n < NST; n++)
            hh[n] = __expf(dtv * Ar[n]) * hh[n] + du * bb[n];
    }
    S[c * DI + d] = ssum;
#pragma unroll
    for (int n = 0; n < NST; n++) hend[hidx(n, c, d)] = hh[n];
}

__global__ void scanB_kernel(const float* __restrict__ S, float* __restrict__ hend,
                             const void* __restrict__ A_log, size_t aofs, int f32) {
    int i = blockIdx.x * 256 + threadIdx.x;   // i < DI*NST
    int d = i & (DI - 1), n = i >> 11;
    float A = -expf(ldin(A_log, aofs + (size_t)d * NST + n, f32));
    float H = 0.f;
    for (int c = 0; c < NCHUNK; c++) {
        size_t o = hidx(n, c, d);
        float he = hend[o];
        hend[o] = H;
        H = __expf(A * S[c * DI + d]) * H + he;
    }
}

__global__ void scanC_kernel(const float* __restrict__ xp, const float* __restrict__ xz,
                             const void* __restrict__ cw, size_t cwofs,
                             const void* __restrict__ cb, size_t cbofs,
                             const void* __restrict__ dtw, size_t dtwofs,
                             const void* __restrict__ dtb, size_t dtbofs,
                             const void* __restrict__ A_log, size_t aofs,
                             const void* __restrict__ Dp, size_t dofs,
                             const float* __restrict__ hcar, bf16* __restrict__ y16, int f32) {
    int c = blockIdx.y;
    int d = blockIdx.x * 256 + threadIdx.x;
    __shared__ float xps[CLEN * XPS];
    for (int i = threadIdx.x; i < CLEN * XPS; i += 256) xps[i] = xp[c * CLEN * XPS + i];
    __syncthreads();
    float dw = ldin(dtw, dtwofs + d, f32);
    float db = ldin(dtb, dtbofs + d, f32);
    float Dpv = ldin(Dp, dofs + d, f32);
    float c0 = ldin(cw, cwofs + (size_t)d * KC + 0, f32);
    float c1 = ldin(cw, cwofs + (size_t)d * KC + 1, f32);
    float c2 = ldin(cw, cwofs + (size_t)d * KC + 2, f32);
    float c3 = ldin(cw, cwofs + (size_t)d * KC + 3, f32);
    float cbv = ldin(cb, cbofs + d, f32);
    float Ar[NST], hh[NST];
#pragma unroll
    for (int n = 0; n < NST; n++) {
        Ar[n] = -expf(ldin(A_log, aofs + (size_t)d * NST + n, f32));
        hh[n] = hcar[hidx(n, c, d)];
    }
    int tb = c * CLEN;
    float w0 = (tb >= 3) ? xz[(size_t)(tb - 3) * (2 * DI) + d] : 0.f;
    float w1 = (tb >= 2) ? xz[(size_t)(tb - 2) * (2 * DI) + d] : 0.f;
    float w2 = (tb >= 1) ? xz[(size_t)(tb - 1) * (2 * DI) + d] : 0.f;
    for (int tt = 0; tt < CLEN; tt++) {
        int t = tb + tt;
        float cur = xz[(size_t)t * (2 * DI) + d];
        float s0 = cbv + c0 * w0 + c1 * w1 + c2 * w2 + c3 * cur;
        float uvv = s0 / (1.f + __expf(-s0));
        w0 = w1; w1 = w2; w2 = cur;
        float s = xps[tt * XPS] * dw + db;
        float dtv = (s > 20.f) ? s : log1pf(__expf(s));
        float du = dtv * uvv;
        const float* bb = &xps[tt * XPS + 1];
        const float* cc = &xps[tt * XPS + 1 + NST];
        float accv = 0.f;
#pragma unroll
        for (int n = 0; n < NST; n++) {
            hh[n] = __expf(dtv * Ar[n]) * hh[n] + du * bb[n];
            accv += hh[n] * cc[n];
        }
        float z = xz[(size_t)t * (2 * DI) + DI + d];
        float sz = z / (1.f + __expf(-z));
        y16[(size_t)t * DI + d] = __float2bfloat16((accv + uvv * Dpv) * sz);
    }
}

extern "C" void kernel_launch(void* const* d_in, const int* in_sizes, int n_in,
                              void* d_out, int out_size, void* d_ws, size_t ws_size,
                              hipStream_t stream) {
    const int*  idx       = (const int*)d_in[0];
    const void* emb       = d_in[1];
    const void* norm_w    = d_in[2];
    const void* in_proj_w = d_in[3];
    const void* conv_w    = d_in[4];
    const void* conv_b    = d_in[5];
    const void* x_proj_w  = d_in[6];
    const void* dt_proj_w = d_in[7];
    const void* dt_proj_b = d_in[8];
    const void* A_log     = d_in[9];
    const void* D_param   = d_in[10];
    const void* out_proj_w= d_in[11];
    const void* norm_f_w  = d_in[12];

    // ---- workspace layout (float offsets); base peak ~93 MB ----
    float* ws   = (float*)d_ws;
    float* xz   = ws;                              //  8M fl (TT*2*DI)
    float* hend = ws + 12582912;                   //  2M fl (NST*NCHUNK*DI)
    bf16*  W16A = (bf16*)(ws + 14680064);          //  per-layer in_proj scratch (fallback)
    bf16*  W16B = (bf16*)(ws + 16777216);          //  per-layer out_proj scratch (fallback)
    float* S    = ws + 17825792;                   //  131072 fl (NCHUNK*DI)
    float* xp   = ws + 17956864;                   //  67584 fl (TT*XPS)
    float* x    = ws + 18024448;                   //  2M fl (TT*DM)
    bf16*  xn16 = (bf16*)(ws + 20121600);          //  2M bf16 (TT*DM)
    bf16*  y16  = (bf16*)(ws + 21170176);          //  4M bf16 (TT*DI)
    bf16*  embOv= (bf16*)ws;                       //  overlay emb16 (fallback; dead at logits)
    // upfront-conversion region (used only when ws_size permits):
    bf16*  WinAll = (bf16*)(ws + 23268352);        // 16,777,216 bf16 -> 8,388,608 fl
    bf16*  WoutAll= (bf16*)(ws + 31656960);        //  8,388,608 bf16 -> 4,194,304 fl
    bf16*  EmbAll = (bf16*)(ws + 35851264);        // 32,768,000 bf16 -> 16,384,000 fl
    const size_t need_upfront = (size_t)52235264 * 4;   // ~209 MB

    long long esz = in_sizes ? (long long)in_sizes[1] : -1;
    int isf32 = (esz == (long long)VOCAB * DM * 2) ? 0 : 1;
    int upfront = isf32 && (ws_size >= need_upfront);

    if (upfront) {
        int n8A = NLAYER * 2 * DI * DM / 8, n8B = NLAYER * DM * DI / 8;
        cvt8_dual_kernel<<<(n8A + n8B + 255) / 256, 256, 0, stream>>>(
            (const float*)in_proj_w, (unsigned short*)WinAll, n8A,
            (const float*)out_proj_w, (unsigned short*)WoutAll, n8B);
        int n8E = VOCAB * DM / 8;
        cvt8_dual_kernel<<<(n8E + 255) / 256, 256, 0, stream>>>(
            (const float*)emb, (unsigned short*)EmbAll, n8E, nullptr, nullptr, 0);
    }

    embed_rms_kernel<<<TT, 256, 0, stream>>>(idx, emb, norm_w, x, xn16, isf32);

    for (int l = 0; l < NLAYER; l++) {
        const bf16* Bin;
        const bf16* Bout;
        if (!isf32) {
            Bin  = (const bf16*)in_proj_w  + (size_t)l * 2 * DI * DM;
            Bout = (const bf16*)out_proj_w + (size_t)l * DM * DI;
        } else if (upfront) {
            Bin  = WinAll  + (size_t)l * 2 * DI * DM;
            Bout = WoutAll + (size_t)l * DM * DI;
        } else {
            int n8A = 2 * DI * DM / 8, n8B = DM * DI / 8;
            cvt8_dual_kernel<<<(n8A + n8B + 255) / 256, 256, 0, stream>>>(
                (const float*)in_proj_w + (size_t)l * 2 * DI * DM, (unsigned short*)W16A, n8A,
                (const float*)out_proj_w + (size_t)l * DM * DI, (unsigned short*)W16B, n8B);
            Bin = W16A; Bout = W16B;
        }

        if (l > 0)
            rmsnorm_kernel<<<TT, 256, 0, stream>>>(x, norm_w, (size_t)l * DM, xn16, isf32);
        // in_proj: M=2048 N=4096 K=1024, BM=128 -> 512 wg = 2 blocks/CU exact
        gemm_mfma<128><<<(TT / 128) * (2 * DI / 128), 256, 0, stream>>>(
            xn16, Bin, nullptr, xz, nullptr, TT / 128, 2 * DI / 128, DM);
        cxp_kernel<<<TT, 256, 0, stream>>>(
            xz, conv_w, (size_t)l * DI * KC, conv_b, (size_t)l * DI,
            x_proj_w, (size_t)l * XPS * DI, xp, isf32);
        scanA_kernel<<<dim3(DI / 256, NCHUNK), 256, 0, stream>>>(
            xp, xz, conv_w, (size_t)l * DI * KC, conv_b, (size_t)l * DI,
            dt_proj_w, (size_t)l * DI, dt_proj_b, (size_t)l * DI,
            A_log, (size_t)l * DI * NST, S, hend, isf32);
        scanB_kernel<<<DI * NST / 256, 256, 0, stream>>>(
            S, hend, A_log, (size_t)l * DI * NST, isf32);
        scanC_kernel<<<dim3(DI / 256, NCHUNK), 256, 0, stream>>>(
            xp, xz, conv_w, (size_t)l * DI * KC, conv_b, (size_t)l * DI,
            dt_proj_w, (size_t)l * DI, dt_proj_b, (size_t)l * DI,
            A_log, (size_t)l * DI * NST, D_param, (size_t)l * DI, hend, y16, isf32);
        // out_proj: M=2048 N=1024 K=2048, BM=32 -> 512 wg, 4 blocks/CU
        gemm_mfma<32><<<(TT / 32) * (DM / 128), 256, 0, stream>>>(
            y16, Bout, x, x, nullptr, TT / 32, DM / 128, DI);
    }

    rmsnorm_kernel<<<TT, 256, 0, stream>>>(x, norm_f_w, 0, xn16, isf32);

    const bf16* Bemb;
    if (!isf32) {
        Bemb = (const bf16*)emb;
    } else if (upfront) {
        Bemb = EmbAll;
    } else {
        int n8 = VOCAB * DM / 8;
        cvt8_dual_kernel<<<(n8 + 255) / 256, 256, 0, stream>>>(
            (const float*)emb, (unsigned short*)embOv, n8, nullptr, nullptr, 0);
        Bemb = embOv;
    }
    if (isf32)
        gemm_mfma<128><<<(TT / 128) * (VOCAB / 128), 256, 0, stream>>>(
            xn16, Bemb, nullptr, (float*)d_out, nullptr, TT / 128, VOCAB / 128, DM);
    else
        gemm_mfma<128><<<(TT / 128) * (VOCAB / 128), 256, 0, stream>>>(
            xn16, Bemb, nullptr, nullptr, (bf16*)d_out, TT / 128, VOCAB / 128, DM);
}